// Round 2
// baseline (321.550 us; speedup 1.0000x reference)
//
#include <hip/hip_runtime.h>

#define EPS 1e-5f

constexpr int F    = 256;        // features
constexpr int F4   = 64;         // float4 per row
constexpr int ROWS = 32 * 4096;  // 131072 rows
constexpr int NG   = ROWS / 32;  // 4096 groups of 32 rows (4 waves x 8 rows)
constexpr int NBLK = 1024;       // 4 blocks/CU x 256 CU
constexpr int ITER = NG / NBLK;  // 4 groups per block

// native vector type for nontemporal builtin (HIP float4 is a class)
typedef float vfloat4 __attribute__((ext_vector_type(4)));

// ---------------------------------------------------------------------------
// Kernel 1: per-feature partial sums over masked rows, fused with the
// finalize via the deadlock-free last-block ticket pattern (no cooperative
// launch -- graph capture rejects it; no spin-wait -- no residency
// assumption). Partials are ROW-major p[block][feature] so the writer's
// float4 store and the finalize's per-iteration reads are both coalesced.
// ---------------------------------------------------------------------------
__global__ void __launch_bounds__(256, 4) reduce_finalize_kernel(
    const float4* __restrict__ x4, const int4* __restrict__ mask4,
    const float* __restrict__ gamma, const float* __restrict__ beta,
    float* __restrict__ pS1, float* __restrict__ pS2,   // [NBLK][F] row-major
    float* __restrict__ pCnt,                            // [NBLK]
    float* __restrict__ scale, float* __restrict__ shift,
    unsigned int* __restrict__ ticket)
{
    const int lane = threadIdx.x & 63;
    const int wv   = threadIdx.x >> 6;
    const int bid  = blockIdx.x;

    __shared__ float4 sh1[256];
    __shared__ float4 sh2[256];
    __shared__ float  shc[4];
    __shared__ int    isLast;
    __shared__ float  cntAll;

    // ---------------- Phase A: masked partial sums ----------------
    float4 s1 = {0.f, 0.f, 0.f, 0.f};
    float4 s2 = {0.f, 0.f, 0.f, 0.f};
    float  cnt = 0.f;

    #pragma unroll
    for (int i = 0; i < ITER; ++i) {
        const int g    = bid + i * NBLK;
        const int row0 = g * 32 + wv * 8;
        const int4 mlo = mask4[(row0 >> 2) + 0];   // rows row0..row0+3
        const int4 mhi = mask4[(row0 >> 2) + 1];   // rows row0+4..row0+7
        const int m[8] = {mlo.x, mlo.y, mlo.z, mlo.w, mhi.x, mhi.y, mhi.z, mhi.w};
        const float4* p = x4 + (size_t)row0 * F4 + lane;

        float4 v[8];
        #pragma unroll
        for (int j = 0; j < 8; ++j)
            if (m[j] > 0) v[j] = p[j * F4];        // loads batched, uses below
        #pragma unroll
        for (int j = 0; j < 8; ++j)
            if (m[j] > 0) {
                const float4 w = v[j];
                s1.x += w.x; s1.y += w.y; s1.z += w.z; s1.w += w.w;
                s2.x = fmaf(w.x, w.x, s2.x); s2.y = fmaf(w.y, w.y, s2.y);
                s2.z = fmaf(w.z, w.z, s2.z); s2.w = fmaf(w.w, w.w, s2.w);
                cnt += 1.f;
            }
    }

    sh1[threadIdx.x] = s1;
    sh2[threadIdx.x] = s2;
    if (lane == 0) shc[wv] = cnt;                  // cnt is wave-uniform
    __syncthreads();

    if (wv == 0) {
        float4 a = sh1[lane];
        float4 b = sh2[lane];
        #pragma unroll
        for (int w = 1; w < 4; ++w) {
            const float4 c = sh1[w * 64 + lane];
            const float4 d = sh2[w * 64 + lane];
            a.x += c.x; a.y += c.y; a.z += c.z; a.w += c.w;
            b.x += d.x; b.y += d.y; b.z += d.z; b.w += d.w;
        }
        // row-major: features lane*4..lane*4+3 of block bid, one float4 store
        reinterpret_cast<float4*>(pS1)[bid * F4 + lane] = a;
        reinterpret_cast<float4*>(pS2)[bid * F4 + lane] = b;
        if (lane == 0)
            pCnt[bid] = shc[0] + shc[1] + shc[2] + shc[3];
    }
    __syncthreads();                               // partial stores issued

    // ---------------- Release + ticket ----------------
    if (threadIdx.x == 0) {
        __threadfence();                           // agent-scope release (L2 wb)
        const unsigned int old = atomicAdd(ticket, 1u);
        isLast = (old == (unsigned int)(gridDim.x - 1)) ? 1 : 0;
    }
    __syncthreads();
    if (!isLast) return;                           // 1023 blocks retire

    // ---------------- Finalize (last block only) ----------------
    __threadfence();                               // agent-scope acquire (L2 inv)
    const int t = threadIdx.x;                     // thread t == feature t

    float a = 0.f, b = 0.f;
    #pragma unroll 8
    for (int bk = 0; bk < NBLK; ++bk) {            // coalesced: 256 thr x 4B
        a += pS1[bk * F + t];
        b += pS2[bk * F + t];
    }
    float c = pCnt[t] + pCnt[t + 256] + pCnt[t + 512] + pCnt[t + 768];
    #pragma unroll
    for (int off = 32; off > 0; off >>= 1)
        c += __shfl_down(c, off);
    if (lane == 0) shc[wv] = c;
    __syncthreads();
    if (t == 0) cntAll = shc[0] + shc[1] + shc[2] + shc[3];
    __syncthreads();

    const float inv_cnt = 1.f / cntAll;
    const float mean = a * inv_cnt;
    const float var  = fmaf(-mean, mean, b * inv_cnt);
    const float inv  = rsqrtf(var + EPS);
    const float g    = gamma[t] * inv;
    scale[t] = g;
    shift[t] = fmaf(-mean, g, beta[t]);
}

// ---------------------------------------------------------------------------
// Kernel 2: out = mask ? x*scale + shift : x  (verified in round 0)
// Branchless, 8 rows/wave/iter: 8 loads batched, 8 non-temporal stores.
// ---------------------------------------------------------------------------
__device__ __forceinline__ vfloat4 sel4(int m, const float4 v,
                                        const float4 sc, const float4 sh)
{
    vfloat4 o;
    o.x = (m > 0) ? fmaf(v.x, sc.x, sh.x) : v.x;
    o.y = (m > 0) ? fmaf(v.y, sc.y, sh.y) : v.y;
    o.z = (m > 0) ? fmaf(v.z, sc.z, sh.z) : v.z;
    o.w = (m > 0) ? fmaf(v.w, sc.w, sh.w) : v.w;
    return o;
}

__global__ void __launch_bounds__(256, 4) norm_kernel(
    const float4* __restrict__ x4, const int4* __restrict__ mask4,
    const float4* __restrict__ scale4, const float4* __restrict__ shift4,
    float4* __restrict__ out4)
{
    const int lane = threadIdx.x & 63;
    const int wv   = threadIdx.x >> 6;
    const float4 sc = scale4[lane];
    const float4 sh = shift4[lane];

    vfloat4* __restrict__ outv = reinterpret_cast<vfloat4*>(out4);

    for (int g = blockIdx.x; g < NG; g += gridDim.x) {
        const int row0 = g * 32 + wv * 8;
        const int4 mlo = mask4[(row0 >> 2) + 0];
        const int4 mhi = mask4[(row0 >> 2) + 1];
        const int m[8] = {mlo.x, mlo.y, mlo.z, mlo.w, mhi.x, mhi.y, mhi.z, mhi.w};
        const size_t base = (size_t)row0 * F4 + lane;

        float4 v[8];
        #pragma unroll
        for (int j = 0; j < 8; ++j) v[j] = x4[base + (size_t)j * F4];
        #pragma unroll
        for (int j = 0; j < 8; ++j)
            __builtin_nontemporal_store(sel4(m[j], v[j], sc, sh),
                                        &outv[base + (size_t)j * F4]);
    }
}

// ---------------------------------------------------------------------------
extern "C" void kernel_launch(void* const* d_in, const int* in_sizes, int n_in,
                              void* d_out, int out_size, void* d_ws, size_t ws_size,
                              hipStream_t stream)
{
    const float* x     = (const float*)d_in[0];
    const int*   mask  = (const int*)d_in[1];
    const float* gamma = (const float*)d_in[2];
    const float* beta  = (const float*)d_in[3];
    float* out = (float*)d_out;
    float* ws  = (float*)d_ws;

    // ws layout (floats): pS1[NBLK*F] | pS2[NBLK*F] | pCnt[NBLK] |
    //                     scale[F] | shift[F] | ticket
    // all float4-view offsets 16B-aligned; ~2.1 MiB total.
    float* pS1   = ws;
    float* pS2   = pS1 + (size_t)NBLK * F;
    float* pCnt  = pS2 + (size_t)NBLK * F;
    float* scale = pCnt + NBLK;
    float* shift = scale + F;
    unsigned int* ticket = (unsigned int*)(shift + F);

    hipMemsetAsync(ticket, 0, sizeof(unsigned int), stream);

    reduce_finalize_kernel<<<NBLK, 256, 0, stream>>>(
        (const float4*)x, (const int4*)mask, gamma, beta,
        pS1, pS2, pCnt, scale, shift, ticket);
    norm_kernel<<<NBLK, 256, 0, stream>>>(
        (const float4*)x, (const int4*)mask,
        (const float4*)scale, (const float4*)shift, (float4*)out);
}

// Round 3
// 248.735 us; speedup vs baseline: 1.2927x; 1.2927x over previous
//
#include <hip/hip_runtime.h>

#define EPS 1e-5f

constexpr int F    = 256;        // features
constexpr int F4   = 64;         // float4 per row
constexpr int ROWS = 32 * 4096;  // 131072 rows
constexpr int NG   = ROWS / 32;  // 4096 groups of 32 rows (4 waves x 8 rows)
constexpr int NBLK = 1024;       // 4 blocks/CU x 256 CU
constexpr int ITER = NG / NBLK;  // 4 groups per block

// native vector type for nontemporal builtin (HIP float4 is a class)
typedef float vfloat4 __attribute__((ext_vector_type(4)));

// ---------------------------------------------------------------------------
// Pass 1: per-feature partial sums over masked rows.
// Compile-time 4-iteration loop (full unroll -> deep vmcnt pipelining),
// 8 consecutive rows per wave per iter, wave-uniform mask branches.
// Partials column-major pS[f*NBLK + b] (contiguous in b for pass 2).
// ---------------------------------------------------------------------------
__global__ void __launch_bounds__(256, 4) reduce_kernel(
    const float4* __restrict__ x4, const int4* __restrict__ mask4,
    float* __restrict__ pS1, float* __restrict__ pS2,
    float* __restrict__ pCnt)
{
    const int lane = threadIdx.x & 63;
    const int wv   = threadIdx.x >> 6;
    const int bid  = blockIdx.x;

    float4 s1 = {0.f, 0.f, 0.f, 0.f};
    float4 s2 = {0.f, 0.f, 0.f, 0.f};
    float  cnt = 0.f;

    #pragma unroll
    for (int i = 0; i < ITER; ++i) {
        const int g    = bid + i * NBLK;
        const int row0 = g * 32 + wv * 8;
        const int4 mlo = mask4[(row0 >> 2) + 0];   // rows row0..row0+3
        const int4 mhi = mask4[(row0 >> 2) + 1];   // rows row0+4..row0+7
        const int m[8] = {mlo.x, mlo.y, mlo.z, mlo.w, mhi.x, mhi.y, mhi.z, mhi.w};
        const float4* p = x4 + (size_t)row0 * F4 + lane;

        float4 v[8];
        #pragma unroll
        for (int j = 0; j < 8; ++j)
            if (m[j] > 0) v[j] = p[j * F4];        // loads batched, uses below
        #pragma unroll
        for (int j = 0; j < 8; ++j)
            if (m[j] > 0) {
                const float4 w = v[j];
                s1.x += w.x; s1.y += w.y; s1.z += w.z; s1.w += w.w;
                s2.x = fmaf(w.x, w.x, s2.x); s2.y = fmaf(w.y, w.y, s2.y);
                s2.z = fmaf(w.z, w.z, s2.z); s2.w = fmaf(w.w, w.w, s2.w);
                cnt += 1.f;
            }
    }

    __shared__ float4 sh1[256];
    __shared__ float4 sh2[256];
    __shared__ float  shc[4];
    sh1[threadIdx.x] = s1;
    sh2[threadIdx.x] = s2;
    if (lane == 0) shc[wv] = cnt;                  // cnt is wave-uniform
    __syncthreads();

    if (wv == 0) {
        float4 a = sh1[lane];
        float4 b = sh2[lane];
        #pragma unroll
        for (int w = 1; w < 4; ++w) {
            const float4 c = sh1[w * 64 + lane];
            const float4 d = sh2[w * 64 + lane];
            a.x += c.x; a.y += c.y; a.z += c.z; a.w += c.w;
            b.x += d.x; b.y += d.y; b.z += d.z; b.w += d.w;
        }
        const int f0 = lane * 4;
        pS1[(size_t)(f0 + 0) * NBLK + bid] = a.x;
        pS1[(size_t)(f0 + 1) * NBLK + bid] = a.y;
        pS1[(size_t)(f0 + 2) * NBLK + bid] = a.z;
        pS1[(size_t)(f0 + 3) * NBLK + bid] = a.w;
        pS2[(size_t)(f0 + 0) * NBLK + bid] = b.x;
        pS2[(size_t)(f0 + 1) * NBLK + bid] = b.y;
        pS2[(size_t)(f0 + 2) * NBLK + bid] = b.z;
        pS2[(size_t)(f0 + 3) * NBLK + bid] = b.w;
        if (lane == 0)
            pCnt[bid] = shc[0] + shc[1] + shc[2] + shc[3];
    }
}

// ---------------------------------------------------------------------------
// Pass 2: fold partials -> scale/shift. One block per feature, 64 threads.
// Column is contiguous (column-major) -> float4 loads, 1 KB per wave-instr:
// 4 float4 per thread per array instead of 16 scalar loads (round-0 version).
// ---------------------------------------------------------------------------
__global__ void __launch_bounds__(64) finalize_kernel(
    const float* __restrict__ pS1, const float* __restrict__ pS2,
    const float* __restrict__ pCnt,
    const float* __restrict__ gamma, const float* __restrict__ beta,
    float* __restrict__ scale, float* __restrict__ shift)
{
    const int f = blockIdx.x;
    const int t = threadIdx.x;

    const float4* c1 = reinterpret_cast<const float4*>(pS1 + (size_t)f * NBLK);
    const float4* c2 = reinterpret_cast<const float4*>(pS2 + (size_t)f * NBLK);
    const float4* cc = reinterpret_cast<const float4*>(pCnt);

    float s1 = 0.f, s2 = 0.f, c = 0.f;
    #pragma unroll
    for (int i = 0; i < NBLK / 4 / 64; ++i) {      // 4 float4 per thread
        const float4 a = c1[t + i * 64];
        const float4 b = c2[t + i * 64];
        const float4 d = cc[t + i * 64];
        s1 += a.x + a.y + a.z + a.w;
        s2 += b.x + b.y + b.z + b.w;
        c  += d.x + d.y + d.z + d.w;
    }
    #pragma unroll
    for (int off = 32; off > 0; off >>= 1) {
        s1 += __shfl_down(s1, off);
        s2 += __shfl_down(s2, off);
        c  += __shfl_down(c,  off);
    }
    if (t == 0) {
        const float inv_cnt = 1.f / c;
        const float mean = s1 * inv_cnt;
        const float var  = fmaf(-mean, mean, s2 * inv_cnt);
        const float inv  = rsqrtf(var + EPS);
        const float g    = gamma[f] * inv;
        scale[f] = g;
        shift[f] = fmaf(-mean, g, beta[f]);
    }
}

// ---------------------------------------------------------------------------
// Pass 3: out = mask ? x*scale + shift : x   (verbatim round-0 verified)
// Branchless, 8 rows/wave/iter: 8 loads batched, 8 non-temporal stores
// (out is write-once -> don't evict x from L2/L3; reduce's x re-read then
// hits the lines this pass would otherwise displace).
// ---------------------------------------------------------------------------
__device__ __forceinline__ vfloat4 sel4(int m, const float4 v,
                                        const float4 sc, const float4 sh)
{
    vfloat4 o;
    o.x = (m > 0) ? fmaf(v.x, sc.x, sh.x) : v.x;
    o.y = (m > 0) ? fmaf(v.y, sc.y, sh.y) : v.y;
    o.z = (m > 0) ? fmaf(v.z, sc.z, sh.z) : v.z;
    o.w = (m > 0) ? fmaf(v.w, sc.w, sh.w) : v.w;
    return o;
}

__global__ void __launch_bounds__(256, 4) norm_kernel(
    const float4* __restrict__ x4, const int4* __restrict__ mask4,
    const float4* __restrict__ scale4, const float4* __restrict__ shift4,
    float4* __restrict__ out4)
{
    const int lane = threadIdx.x & 63;
    const int wv   = threadIdx.x >> 6;
    const float4 sc = scale4[lane];
    const float4 sh = shift4[lane];

    vfloat4* __restrict__ outv = reinterpret_cast<vfloat4*>(out4);

    for (int g = blockIdx.x; g < NG; g += gridDim.x) {
        const int row0 = g * 32 + wv * 8;
        const int4 mlo = mask4[(row0 >> 2) + 0];
        const int4 mhi = mask4[(row0 >> 2) + 1];
        const int m[8] = {mlo.x, mlo.y, mlo.z, mlo.w, mhi.x, mhi.y, mhi.z, mhi.w};
        const size_t base = (size_t)row0 * F4 + lane;

        float4 v[8];
        #pragma unroll
        for (int j = 0; j < 8; ++j) v[j] = x4[base + (size_t)j * F4];
        #pragma unroll
        for (int j = 0; j < 8; ++j)
            __builtin_nontemporal_store(sel4(m[j], v[j], sc, sh),
                                        &outv[base + (size_t)j * F4]);
    }
}

// ---------------------------------------------------------------------------
extern "C" void kernel_launch(void* const* d_in, const int* in_sizes, int n_in,
                              void* d_out, int out_size, void* d_ws, size_t ws_size,
                              hipStream_t stream)
{
    const float* x     = (const float*)d_in[0];
    const int*   mask  = (const int*)d_in[1];
    const float* gamma = (const float*)d_in[2];
    const float* beta  = (const float*)d_in[3];
    float* out = (float*)d_out;
    float* ws  = (float*)d_ws;

    // ws layout (floats): pS1[F*NBLK] | pS2[F*NBLK] | pCnt[NBLK] |
    //                     scale[F] | shift[F]        (~2.1 MiB, all 16B-aligned)
    float* pS1   = ws;
    float* pS2   = pS1 + (size_t)F * NBLK;
    float* pCnt  = pS2 + (size_t)F * NBLK;
    float* scale = pCnt + NBLK;
    float* shift = scale + F;

    reduce_kernel<<<NBLK, 256, 0, stream>>>(
        (const float4*)x, (const int4*)mask, pS1, pS2, pCnt);
    finalize_kernel<<<F, 64, 0, stream>>>(
        pS1, pS2, pCnt, gamma, beta, scale, shift);
    norm_kernel<<<NBLK, 256, 0, stream>>>(
        (const float4*)x, (const int4*)mask, (const float4*)scale,
        (const float4*)shift, (float4*)out);
}